// Round 12
// baseline (143.910 us; speedup 1.0000x reference)
//
#include <hip/hip_runtime.h>
#include <math.h>

typedef unsigned short u16;
typedef unsigned int u32;
typedef __attribute__((ext_vector_type(8))) short bf16x8;   // 8 bf16 = 4 VGPR (MFMA A/B frag)
typedef __attribute__((ext_vector_type(4))) float f32x4;    // MFMA C/D frag
typedef __attribute__((ext_vector_type(2))) float f32x2;    // packed fp32 pair (v_pk_fma_f32)

__device__ __forceinline__ u16 f32_to_bf16(float f) {
    u32 u = __float_as_uint(f);
    u32 r = u + 0x7FFFu + ((u >> 16) & 1u);   // round-to-nearest-even
    return (u16)(r >> 16);
}
__device__ __forceinline__ u32 pack2(u16 a, u16 b) { return (u32)a | ((u32)b << 16); }

// HW packed f32->bf16 RNE: lo = bf16(a), hi = bf16(b). 1 inst vs 9 for manual RNE+perm.
__device__ __forceinline__ u32 cvt_pk_bf16(float a, float b) {
    u32 r;
    asm("v_cvt_pk_bf16_f32 %0, %1, %2" : "=v"(r) : "v"(a), "v"(b));
    return r;
}

// fast tanh via hardware exp
__device__ __forceinline__ float fast_tanh(float x) {
    float e = __expf(2.f * x);
    return 1.f - 2.f / (e + 1.f);
}

// ---------------- quantum gate helpers (prep only; precise libm) ----------------
template<int STRIDE>
__device__ __forceinline__ void ry_gate(float st[16], float theta) {
    float s, c;
    sincosf(theta * 0.5f, &s, &c);
#pragma unroll
    for (int i = 0; i < 16; ++i) {
        if (i & STRIDE) continue;
        float s0 = st[i], s1 = st[i | STRIDE];
        st[i]          = c * s0 - s * s1;
        st[i | STRIDE] = fmaf(s, s0, c * s1);
    }
}
template<int CS, int TS>
__device__ __forceinline__ void cnot_gate(float st[16]) {
#pragma unroll
    for (int i = 0; i < 16; ++i) {
        if ((i & CS) && !(i & TS)) {
            float tmp = st[i]; st[i] = st[i | TS]; st[i | TS] = tmp;
        }
    }
}

// ---------------- Prep: fcw transpose->bf16, w2->bf16 frag layout, circuit matrix M ----------
// whi: [f][k = op*64+oc] (k_ref = oc*16+op). w2b: [(t*64+oc)*32+ic] bf16.
__global__ __launch_bounds__(256) void prep_kernel(
    const float* __restrict__ fcw, const float* __restrict__ w2,
    const float* __restrict__ qp,
    u16* __restrict__ whi, u16* __restrict__ w2b, float* __restrict__ Mg)
{
    const int f  = blockIdx.x;         // 0..63
    const int k0 = threadIdx.x * 4;    // 0..1020
    u16 hv[4];
#pragma unroll
    for (int i = 0; i < 4; ++i) {
        int k  = k0 + i;
        int op = k >> 6, oc = k & 63;
        hv[i] = f32_to_bf16(fcw[(size_t)(oc * 16 + op) * 64 + f]);
    }
    *(uint2*)(whi + (size_t)f * 1024 + k0) = make_uint2(pack2(hv[0], hv[1]), pack2(hv[2], hv[3]));

    if (threadIdx.x < 96) {
        const int j  = threadIdx.x;
        const int ic = j / 3, t = j - ic * 3;
        w2b[(t * 64 + f) * 32 + ic] = f32_to_bf16(w2[f * 96 + j]);
    }

    if (blockIdx.x == 0 && threadIdx.x < 16) {
        const int j = threadIdx.x;
        float st[16];
#pragma unroll
        for (int i = 0; i < 16; ++i) st[i] = (i == j) ? 1.f : 0.f;
        for (int k = 0; k < 6; ++k) {
            cnot_gate<8, 4>(st);   // CNOT(0,1)
            cnot_gate<2, 1>(st);   // CNOT(2,3)
            cnot_gate<4, 2>(st);   // CNOT(1,2)
            ry_gate<8>(st, qp[k * 4 + 0]);
            ry_gate<4>(st, qp[k * 4 + 1]);
            ry_gate<2>(st, qp[k * 4 + 2]);
            ry_gate<1>(st, qp[k * 4 + 3]);
        }
#pragma unroll
        for (int i = 0; i < 16; ++i) Mg[i * 16 + j] = st[i];
    }
}

// ---------------- Fused: conv1 -> conv2(MFMA) -> fc(MFMA) -> quantum epilogue ----------------
// R27 = R26 resubmitted verbatim (R11 bench was an infra failure: "container failed twice";
// the kernel itself was never evaluated).
// R26 = R25 phases, PERSISTENT 4-TILE BLOCKS (grid 512, each block = 4 consecutive 16-sample
// tiles). R25 post-mortem: VALU cuts landed (VALUBusy 29->21, conflicts -25%) but dur flat
// -> VALU was slack; the critical path is the per-block serial latency chain (x HBM load,
// table/af staging, barrier drains, wave-0 epilogue tail) x 8 blocks/CU. R26 amortizes:
//  - tables (prews/Ms/fcbs) + af + bias2 staged ONCE per block (saves 12 L2 b128 + staging
//    x3 tiles);
//  - x PREFETCH: tile t+1's float2 issued at top of tile t (HBM latency hidden under a
//    full tile; conv1 waits only on the OLDER xv -> vmcnt in-order preserved);
//  - epilogue tail OVERLAP: after barrier B, waves 1-7 run conv1/conv2(t+1) (touch only
//    c1h, which fc(t) finished reading before B; part2 is only rewritten after barrier
//    A(t+1), which wave 0 reaches after finishing epilogue(t)) -> the ~800cyc single-wave
//    tail overlaps next-tile conv work at 3 junctions/block. Barriers stay 2/tile. Loop
//    kept rolled (unroll 1) to avoid i-cache bloat.
// Carried invariants: conv1 weight indices wave-uniform (R23); no barrier before conv2
// (conv1 wave wv writes samples {2wv,2wv+1}, conv2 wave wv reads only those); single
// barrier B with all-8-wave partial store to part2 stride 20; epilogue wave 0 full 64-lane
// (s=lane>>2, L=lane&3); cc=(c+L)&3 bank stagger; dual fc accumulator; cvt_pk_bf16 packing.
// (512,4) = VGPR cap 128. Per-sample c1h block (1384 u16): c1T rows p[0,34) stride 40
// (halo rows 0,33 zero); hT aliased op-chunk stride 72. Spill canary: WRITE_SIZE ~0.13MB.
__global__ __launch_bounds__(512, 4) void fused_kernel(
    const float* __restrict__ x,
    const float* __restrict__ w1, const float* __restrict__ b1,
    const u16* __restrict__ w2b, const float* __restrict__ b2,
    const u16* __restrict__ whi,
    const float* __restrict__ fcb,
    const float* __restrict__ prew, const float* __restrict__ preb,
    const float* __restrict__ postw, const float* __restrict__ postb,
    const float* __restrict__ Mg,
    float* __restrict__ out)
{
    __shared__ __align__(16) u16 c1h[16 * 1384];     // 44.3 KB
    __shared__ __align__(16) float part2[2 * 1280];  // 10.2 KB fc half partials, stride 20
    __shared__ float prews[256];                     // 1 KB
    __shared__ float Ms[16][17];                     // 1.1 KB
    __shared__ float fcbs[64];                       // 0.25 KB

    const int tid  = threadIdx.x;
    const int wv   = tid >> 6, lane = tid & 63;
    const int lr   = lane & 15, lq = lane >> 4;

    // ---- stage small tables ONCE (ordered before first epilogue by barriers A and B) ----
    if (tid < 256) {
        prews[tid] = prew[tid];
        Ms[tid >> 4][tid & 15] = Mg[tid];
    }
    if (tid < 64) fcbs[tid] = fcb[tid];

    // ---- x load for tile 0 FIRST (vmcnt in-order: conv1's wait won't drain af loads) ----
    const int s1 = tid >> 5;        // 0..15
    const int pp = tid & 31;        // p = pp+1
    const int j  = 2 * pp;
    const float* xbase = x + (size_t)(blockIdx.x * 64 + s1) * 64;   // 4 tiles * 16 samples
    float2 xv = *(const float2*)(xbase + j);

    // ---- conv2 weight frags ONCE; latency hides under tile-0 conv1 arithmetic ----
    bf16x8 af[3][4];
#pragma unroll
    for (int t = 0; t < 3; ++t)
#pragma unroll
        for (int mt = 0; mt < 4; ++mt)
            af[t][mt] = *(const bf16x8*)(w2b + (size_t)(t * 64 + mt * 16 + lr) * 32 + lq * 8);
    f32x4 bias2[4];
#pragma unroll
    for (int mt = 0; mt < 4; ++mt)
        bias2[mt] = *(const f32x4*)(b2 + mt * 16 + lq * 4);

    // fc addressing (constant across tiles)
    const int g  = wv & 3;
    const int hf = wv >> 2;
    const int n0 = g * 16;
    const u16* ab0 = c1h + (size_t)lr * 1384 + lq * 8;
    const u16* bh0 = whi + (size_t)(n0 + lr) * 1024 + hf * 16 * 32 + lq * 8;

#pragma unroll 1
    for (int t = 0; t < 4; ++t) {
        const int bs = (blockIdx.x * 4 + t) * 16;

        // prefetch next tile's x (issued before this tile's compute; consumed next iter)
        float2 xnext;
        if (t < 3) xnext = *(const float2*)(xbase + (t + 1) * 1024 + j);

        float x0 = xv.x, x1 = xv.y;
        // neighbors via cross-lane (sample boundaries masked to the zero pad):
        float xm1 = __shfl_up(x1, 1);   if (pp == 0)  xm1 = 0.f;
        float xp2 = __shfl_down(x0, 1); if (pp == 31) xp2 = 0.f;

        // ---- conv1 + relu + pool2 -> c1T; packed-pair math -> v_pk_fma_f32 ----
        {
            u16* sbase = c1h + s1 * 1384;
            if (pp == 0 || pp == 31) {      // halo rows 0 and 33
                uint4 z = make_uint4(0, 0, 0, 0);
                uint4* zr = (uint4*)(sbase + (pp == 0 ? 0 : 33) * 40);
                zr[0] = z; zr[1] = z; zr[2] = z; zr[3] = z;
            }
            const f32x2 A1 = {xm1, x0};
            const f32x2 A2 = {x0,  x1};
            const f32x2 A3 = {x1,  xp2};
            u32 row[16];
#pragma unroll
            for (int icp = 0; icp < 16; ++icp) {
                float v[2];
#pragma unroll
                for (int h2 = 0; h2 < 2; ++h2) {
                    int ic = icp * 2 + h2;
                    // wave-uniform indices -> scalar loads on the s-pipe (INVARIANT, R23)
                    float wa = w1[ic * 3], wb = w1[ic * 3 + 1], wc = w1[ic * 3 + 2], bb = b1[ic];
                    f32x2 Y = {bb, bb};
                    Y += wa * A1;
                    Y += wb * A2;
                    Y += wc * A3;
                    v[h2] = fmaxf(fmaxf(Y.x, Y.y), 0.f);   // pool + relu (v_max3)
                }
                row[icp] = cvt_pk_bf16(v[0], v[1]);
            }
            uint4* d = (uint4*)(sbase + (1 + pp) * 40);
            d[0] = make_uint4(row[0],  row[1],  row[2],  row[3]);
            d[1] = make_uint4(row[4],  row[5],  row[6],  row[7]);
            d[2] = make_uint4(row[8],  row[9],  row[10], row[11]);
            d[3] = make_uint4(row[12], row[13], row[14], row[15]);
        }
        // NO barrier: conv1 wave wv wrote samples {2wv,2wv+1}; conv2 wave wv reads only those.

        // ---- conv2 via MFMA (bias as C-init) + pool -> hT aliased into c1h ----
#pragma unroll
        for (int nt = 0; nt < 4; ++nt) {          // wave wv -> samples 2wv, 2wv+1; two q-halves
            const int s  = wv * 2 + (nt >> 1);
            const int qb = (nt & 1) * 16;
            const u16* bp = c1h + s * 1384 + (qb + lr) * 40 + lq * 8;
            bf16x8 bf0 = *(const bf16x8*)(bp);
            bf16x8 bf1 = *(const bf16x8*)(bp + 40);
            bf16x8 bf2 = *(const bf16x8*)(bp + 80);
            const int op = (qb + lr) >> 1;
#pragma unroll
            for (int mt = 0; mt < 4; ++mt) {      // interleaved epilogue: acc live = 4
                f32x4 acc = __builtin_amdgcn_mfma_f32_16x16x32_bf16(af[0][mt], bf0, bias2[mt], 0, 0, 0);
                acc = __builtin_amdgcn_mfma_f32_16x16x32_bf16(af[1][mt], bf1, acc, 0, 0, 0);
                acc = __builtin_amdgcn_mfma_f32_16x16x32_bf16(af[2][mt], bf2, acc, 0, 0, 0);
                float p0 = fmaxf(fmaxf(acc[0], __shfl_xor(acc[0], 1)), 0.f);
                float p1 = fmaxf(fmaxf(acc[1], __shfl_xor(acc[1], 1)), 0.f);
                float p2 = fmaxf(fmaxf(acc[2], __shfl_xor(acc[2], 1)), 0.f);
                float p3 = fmaxf(fmaxf(acc[3], __shfl_xor(acc[3], 1)), 0.f);
                if (!(lane & 1)) {
                    *(uint2*)(c1h + s * 1384 + op * 72 + mt * 16 + lq * 4) =
                        make_uint2(cvt_pk_bf16(p0, p1), cvt_pk_bf16(p2, p3));
                }
            }
        }
        __syncthreads();   // barrier A: fc reads hT across all samples/waves
                           // (also protects part2: epilogue(t-1) finished before wave 0 got here)

        // ---- fc via MFMA on 8 waves, fully unrolled, dual accumulator ----
        f32x4 accA = {0.f, 0.f, 0.f, 0.f};
        f32x4 accB = {0.f, 0.f, 0.f, 0.f};
#pragma unroll
        for (int i = 0; i < 16; i += 2) {
            const int kcA = hf * 16 + i;
            const int kcB = kcA + 1;
            const int aoffA = (kcA >> 1) * 72 + (kcA & 1) * 32;
            const int aoffB = (kcB >> 1) * 72 + (kcB & 1) * 32;
            bf16x8 a0 = *(const bf16x8*)(ab0 + aoffA);
            bf16x8 a1 = *(const bf16x8*)(ab0 + aoffB);
            bf16x8 f0 = *(const bf16x8*)(bh0 + i * 32);
            bf16x8 f1 = *(const bf16x8*)(bh0 + (i + 1) * 32);
            accA = __builtin_amdgcn_mfma_f32_16x16x32_bf16(a0, f0, accA, 0, 0, 0);
            accB = __builtin_amdgcn_mfma_f32_16x16x32_bf16(a1, f1, accB, 0, 0, 0);
        }
        const f32x4 acc0 = accA + accB;
        *(f32x4*)(&part2[hf * 1280 + (n0 + lr) * 20 + lq * 4]) = acc0;
        __syncthreads();   // barrier B: partials visible; waves 1-7 proceed to conv1(t+1)

        // ---- epilogue on WAVE 0 (overlaps waves 1-7's conv1/conv2 of tile t+1) ----
        if (wv == 0) {
            const int L = lane & 3;
            const int s = lane >> 2;

            float a0 = 0.f, a1 = 0.f, a2 = 0.f, a3 = 0.f;
#pragma unroll
            for (int i2 = 0; i2 < 4; ++i2) {
#pragma unroll
                for (int c = 0; c < 4; ++c) {
                    int cc = (c + L) & 3;
                    int ff = L * 16 + i2 * 4 + cc;
                    float hx = fmaxf(part2[ff * 20 + s] + part2[1280 + ff * 20 + s] + fcbs[ff], 0.f);
                    float4 pw = *(const float4*)&prews[ff * 4];
                    a0 = fmaf(hx, pw.x, a0);
                    a1 = fmaf(hx, pw.y, a1);
                    a2 = fmaf(hx, pw.z, a2);
                    a3 = fmaf(hx, pw.w, a3);
                }
            }
            a0 += __shfl_xor(a0, 1); a0 += __shfl_xor(a0, 2);
            a1 += __shfl_xor(a1, 1); a1 += __shfl_xor(a1, 2);
            a2 += __shfl_xor(a2, 1); a2 += __shfl_xor(a2, 2);
            a3 += __shfl_xor(a3, 1); a3 += __shfl_xor(a3, 2);

            const float HP = 1.5707963267948966f;
            float qin[4] = { fast_tanh(a0 + preb[0]) * HP, fast_tanh(a1 + preb[1]) * HP,
                             fast_tanh(a2 + preb[2]) * HP, fast_tanh(a3 + preb[3]) * HP };

            float va[4], vb[4];
            const float RS = 0.70710678118654752f;
#pragma unroll
            for (int w = 0; w < 4; ++w) {
                float sw, cw;
                __sincosf(qin[w] * 0.5f, &sw, &cw);
                va[w] = (cw - sw) * RS;
                vb[w] = (sw + cw) * RS;
            }
            float sv[16];
#pragma unroll
            for (int jj = 0; jj < 16; ++jj) {
                float tt = (jj & 8) ? vb[0] : va[0];
                tt *= (jj & 4) ? vb[1] : va[1];
                tt *= (jj & 2) ? vb[2] : va[2];
                tt *= (jj & 1) ? vb[3] : va[3];
                sv[jj] = tt;
            }
            float z0 = 0.f, z1 = 0.f, z2 = 0.f, z3 = 0.f;
#pragma unroll
            for (int rr = 0; rr < 4; ++rr) {
                const int r = L * 4 + rr;
                float m = 0.f;
#pragma unroll
                for (int jj = 0; jj < 16; ++jj) m = fmaf(Ms[r][jj], sv[jj], m);
                float p = m * m;
                z0 += (r & 8) ? -p : p;
                z1 += (r & 4) ? -p : p;
                z2 += (r & 2) ? -p : p;
                z3 += (r & 1) ? -p : p;
            }
            z0 += __shfl_xor(z0, 1); z0 += __shfl_xor(z0, 2);
            z1 += __shfl_xor(z1, 1); z1 += __shfl_xor(z1, 2);
            z2 += __shfl_xor(z2, 1); z2 += __shfl_xor(z2, 2);
            z3 += __shfl_xor(z3, 1); z3 += __shfl_xor(z3, 2);

            if (L == 0) {
                float tt = postb[0] + z0 * postw[0] + z1 * postw[1] + z2 * postw[2] + z3 * postw[3];
                out[bs + s] = 1.f / (1.f + __expf(-tt));
            }
        }

        xv = xnext;
    }
}

extern "C" void kernel_launch(void* const* d_in, const int* in_sizes, int n_in,
                              void* d_out, int out_size, void* d_ws, size_t ws_size,
                              hipStream_t stream) {
    const float* x     = (const float*)d_in[0];
    const float* w1    = (const float*)d_in[1];
    const float* b1    = (const float*)d_in[2];
    const float* w2    = (const float*)d_in[3];
    const float* b2    = (const float*)d_in[4];
    const float* fcw   = (const float*)d_in[5];
    const float* fcb   = (const float*)d_in[6];
    const float* prew  = (const float*)d_in[7];
    const float* preb  = (const float*)d_in[8];
    const float* qp    = (const float*)d_in[9];
    const float* postw = (const float*)d_in[10];
    const float* postb = (const float*)d_in[11];
    float* out = (float*)d_out;

    u16*   fwhi = (u16*)d_ws;                           // 64*1024 bf16 = 128 KiB
    float* Mg   = (float*)((char*)d_ws + 131072);       // 1 KiB
    u16*   w2b  = (u16*)((char*)d_ws + 132096);         // 12 KiB

    const int B = in_sizes[0] / 64;   // 32768

    prep_kernel<<<dim3(64), dim3(256), 0, stream>>>(fcw, w2, qp, fwhi, w2b, Mg);
    fused_kernel<<<dim3(B / 64), dim3(512), 0, stream>>>(x, w1, b1, w2b, b2,
                                                         fwhi, fcb, prew, preb,
                                                         postw, postb, Mg, out);
}

// Round 13
// 132.783 us; speedup vs baseline: 1.0838x; 1.0838x over previous
//
#include <hip/hip_runtime.h>
#include <math.h>

typedef unsigned short u16;
typedef unsigned int u32;
typedef __attribute__((ext_vector_type(8))) short bf16x8;   // 8 bf16 = 4 VGPR (MFMA A/B frag)
typedef __attribute__((ext_vector_type(4))) float f32x4;    // MFMA C/D frag
typedef __attribute__((ext_vector_type(2))) float f32x2;    // packed fp32 pair (v_pk_fma_f32)

__device__ __forceinline__ u16 f32_to_bf16(float f) {
    u32 u = __float_as_uint(f);
    u32 r = u + 0x7FFFu + ((u >> 16) & 1u);   // round-to-nearest-even
    return (u16)(r >> 16);
}
__device__ __forceinline__ u32 pack2(u16 a, u16 b) { return (u32)a | ((u32)b << 16); }

// HW packed f32->bf16 RNE: lo = bf16(a), hi = bf16(b). 1 inst vs 9 for manual RNE+perm.
__device__ __forceinline__ u32 cvt_pk_bf16(float a, float b) {
    u32 r;
    asm("v_cvt_pk_bf16_f32 %0, %1, %2" : "=v"(r) : "v"(a), "v"(b));
    return r;
}

// fast tanh via hardware exp
__device__ __forceinline__ float fast_tanh(float x) {
    float e = __expf(2.f * x);
    return 1.f - 2.f / (e + 1.f);
}

// ---------------- quantum gate helpers (prep only; precise libm) ----------------
template<int STRIDE>
__device__ __forceinline__ void ry_gate(float st[16], float theta) {
    float s, c;
    sincosf(theta * 0.5f, &s, &c);
#pragma unroll
    for (int i = 0; i < 16; ++i) {
        if (i & STRIDE) continue;
        float s0 = st[i], s1 = st[i | STRIDE];
        st[i]          = c * s0 - s * s1;
        st[i | STRIDE] = fmaf(s, s0, c * s1);
    }
}
template<int CS, int TS>
__device__ __forceinline__ void cnot_gate(float st[16]) {
#pragma unroll
    for (int i = 0; i < 16; ++i) {
        if ((i & CS) && !(i & TS)) {
            float tmp = st[i]; st[i] = st[i | TS]; st[i | TS] = tmp;
        }
    }
}

// ---------------- Prep (R28 REWRITE): coalesced LDS transpose ----------------
// R28 insight: bench dur - fused dur ~= 75us in EVERY round (R15..R25) -> the timed graph
// is {prep; fused} and prep_kernel (old: per-block fcw COLUMN reads, 4KB/16KB lane strides,
// every wave-load = 64 scattered cache lines, 64 blocks on 256 CUs) was the other ~70us.
// New structure: block b = (op = b>>2 in [0,16), q = b&3 oc-quarter).
//  Phase 1: lane f reads fcw[(oc*16+op)*64 + f] -> 256B-coalesced per wave; bf16 -> LDS
//           T2[f][ocl], stride 18 u16 (odd -> 2-way banks = free).
//  Phase 2: thread (f2 = tid>>2, c0 = (tid&3)*4) stores 4 u16 (8B) to
//           whi[f2*1024 + op*64 + q*16 + c0]; 4 lanes = 32B contiguous chunks.
// w2b: blocks 0..23, idx = b*256+tid maps LINEARLY onto w2 layout (f = idx/96, j = idx%96)
//      -> fully coalesced reads; scattered 2B writes (6144 total, trivial).
// Mg: unchanged (block 0, lanes 0-15).
// whi semantics identical to old prep: whi[f*1024 + k] = bf16(fcw[(oc*16+op)*64+f]),
// k = op*64+oc.
__global__ __launch_bounds__(256) void prep_kernel(
    const float* __restrict__ fcw, const float* __restrict__ w2,
    const float* __restrict__ qp,
    u16* __restrict__ whi, u16* __restrict__ w2b, float* __restrict__ Mg)
{
    __shared__ u16 T2[64][18];
    const int tid = threadIdx.x;
    const int b   = blockIdx.x;
    const int op  = b >> 2;      // 0..15
    const int q   = b & 3;       // 0..3

    // Phase 1: coalesced fcw reads -> bf16 -> LDS (transposed)
    {
        const int f  = tid & 63;
        const int wq = tid >> 6;            // 0..3
#pragma unroll
        for (int i = 0; i < 4; ++i) {
            const int ocl = wq * 4 + i;     // 0..15
            const int oc  = q * 16 + ocl;
            T2[f][ocl] = f32_to_bf16(fcw[(size_t)(oc * 16 + op) * 64 + f]);
        }
    }

    // w2b on blocks 0..23: coalesced w2 reads, scattered 2B writes (tiny)
    if (b < 24) {
        const int idx = b * 256 + tid;      // 0..6143 == 64*96
        const int f  = idx / 96;
        const int j  = idx - f * 96;
        const int ic = j / 3, t = j - ic * 3;
        w2b[(t * 64 + f) * 32 + ic] = f32_to_bf16(w2[idx]);
    }

    __syncthreads();

    // Phase 2: LDS -> whi, 8B stores; lanes 0-3 form 32B-contiguous chunks
    {
        const int f2 = tid >> 2;            // 0..63
        const int c0 = (tid & 3) * 4;       // 0,4,8,12
        u16 t0 = T2[f2][c0],     t1 = T2[f2][c0 + 1];
        u16 t2 = T2[f2][c0 + 2], t3 = T2[f2][c0 + 3];
        *(uint2*)(whi + (size_t)f2 * 1024 + op * 64 + q * 16 + c0) =
            make_uint2(pack2(t0, t1), pack2(t2, t3));
    }

    // circuit matrix M (unchanged)
    if (b == 0 && tid < 16) {
        const int j = tid;
        float st[16];
#pragma unroll
        for (int i = 0; i < 16; ++i) st[i] = (i == j) ? 1.f : 0.f;
        for (int k = 0; k < 6; ++k) {
            cnot_gate<8, 4>(st);   // CNOT(0,1)
            cnot_gate<2, 1>(st);   // CNOT(2,3)
            cnot_gate<4, 2>(st);   // CNOT(1,2)
            ry_gate<8>(st, qp[k * 4 + 0]);
            ry_gate<4>(st, qp[k * 4 + 1]);
            ry_gate<2>(st, qp[k * 4 + 2]);
            ry_gate<1>(st, qp[k * 4 + 3]);
        }
#pragma unroll
        for (int i = 0; i < 16; ++i) Mg[i * 16 + j] = st[i];
    }
}

// ---------------- Fused: conv1 -> conv2(MFMA) -> fc(MFMA) -> quantum epilogue ----------------
// Fused = R25 VERBATIM (champion 59.6us, canary clean). R26/R27 persistent-block attempt
// regressed (68.7-80.8us, WRITE 0.128MB->44MB spill from holding xnext+af across the rolled
// loop) - reverted. R25 = R24 barrier-merged structure + conv1 float2+shfl x-load +
// cvt_pk_bf16 packing + fc dual accumulator + epilogue cc=(c+L)&3 bank stagger.
// Carried invariants: conv1 weight indices wave-uniform (R23); no barrier before conv2
// (conv1 wave wv writes samples {2wv,2wv+1}, conv2 wave wv reads only those); single
// barrier B with all-8-wave partial store to part2 stride 20; epilogue wave 0 full 64-lane
// (s=lane>>2, L=lane&3). (512,4) = VGPR cap 128. Per-sample c1h block (1384 u16): c1T rows
// p[0,34) stride 40 (halo rows 0,33 zero); hT aliased op-chunk stride 72.
// Spill canary: WRITE_SIZE ~0.13MB.
__global__ __launch_bounds__(512, 4) void fused_kernel(
    const float* __restrict__ x,
    const float* __restrict__ w1, const float* __restrict__ b1,
    const u16* __restrict__ w2b, const float* __restrict__ b2,
    const u16* __restrict__ whi,
    const float* __restrict__ fcb,
    const float* __restrict__ prew, const float* __restrict__ preb,
    const float* __restrict__ postw, const float* __restrict__ postb,
    const float* __restrict__ Mg,
    float* __restrict__ out)
{
    __shared__ __align__(16) u16 c1h[16 * 1384];     // 44.3 KB
    __shared__ __align__(16) float part2[2 * 1280];  // 10.2 KB fc half partials, stride 20
    __shared__ float prews[256];                     // 1 KB
    __shared__ float Ms[16][17];                     // 1.1 KB
    __shared__ float fcbs[64];                       // 0.25 KB

    const int tid  = threadIdx.x;
    const int bs   = blockIdx.x * 16;
    const int wv   = tid >> 6, lane = tid & 63;
    const int lr   = lane & 15, lq = lane >> 4;

    // ---- stage small tables (ordered before epilogue by barriers A and B) ----
    if (tid < 256) {
        prews[tid] = prew[tid];
        Ms[tid >> 4][tid & 15] = Mg[tid];
    }
    if (tid < 64) fcbs[tid] = fcb[tid];

    // ---- x loads FIRST (vmcnt in-order: conv1's wait won't drain later af loads) ----
    const int s1 = tid >> 5;        // 0..15
    const int pp = tid & 31;        // p = pp+1
    const float* xb = x + (size_t)(bs + s1) * 64;
    const int j = 2 * pp;
    const float2 xv = *(const float2*)(xb + j);   // one coalesced 8B load
    float x0 = xv.x, x1 = xv.y;

    // ---- conv2 weight frags issued now; latency hides under conv1 arithmetic ----
    bf16x8 af[3][4];
#pragma unroll
    for (int t = 0; t < 3; ++t)
#pragma unroll
        for (int mt = 0; mt < 4; ++mt)
            af[t][mt] = *(const bf16x8*)(w2b + (size_t)(t * 64 + mt * 16 + lr) * 32 + lq * 8);
    f32x4 bias2[4];
#pragma unroll
    for (int mt = 0; mt < 4; ++mt)
        bias2[mt] = *(const f32x4*)(b2 + mt * 16 + lq * 4);

    // neighbors via cross-lane (sample boundaries masked to the zero pad):
    float xm1 = __shfl_up(x1, 1);   if (pp == 0)  xm1 = 0.f;
    float xp2 = __shfl_down(x0, 1); if (pp == 31) xp2 = 0.f;

    // ---- conv1 + relu + pool2 -> c1T; packed-pair math (y0,y1) -> v_pk_fma_f32 ----
    {
        u16* sbase = c1h + s1 * 1384;
        if (pp == 0 || pp == 31) {      // halo rows 0 and 33
            uint4 z = make_uint4(0, 0, 0, 0);
            uint4* zr = (uint4*)(sbase + (pp == 0 ? 0 : 33) * 40);
            zr[0] = z; zr[1] = z; zr[2] = z; zr[3] = z;
        }
        const f32x2 A1 = {xm1, x0};
        const f32x2 A2 = {x0,  x1};
        const f32x2 A3 = {x1,  xp2};
        u32 row[16];
#pragma unroll
        for (int icp = 0; icp < 16; ++icp) {
            float v[2];
#pragma unroll
            for (int h2 = 0; h2 < 2; ++h2) {
                int ic = icp * 2 + h2;
                // wave-uniform indices -> scalar loads on the s-pipe (INVARIANT, R23 lesson)
                float wa = w1[ic * 3], wb = w1[ic * 3 + 1], wc = w1[ic * 3 + 2], bb = b1[ic];
                f32x2 Y = {bb, bb};
                Y += wa * A1;
                Y += wb * A2;
                Y += wc * A3;
                v[h2] = fmaxf(fmaxf(Y.x, Y.y), 0.f);   // pool + relu (v_max3)
            }
            row[icp] = cvt_pk_bf16(v[0], v[1]);
        }
        uint4* d = (uint4*)(sbase + (1 + pp) * 40);
        d[0] = make_uint4(row[0],  row[1],  row[2],  row[3]);
        d[1] = make_uint4(row[4],  row[5],  row[6],  row[7]);
        d[2] = make_uint4(row[8],  row[9],  row[10], row[11]);
        d[3] = make_uint4(row[12], row[13], row[14], row[15]);
    }
    // NO barrier: conv1 wave wv wrote samples {2wv,2wv+1}; conv2 wave wv reads only those.
    // Same-wave LDS ops are in-order -> RAW safe without __syncthreads.

    // ---- conv2 via MFMA (bias as C-init) + pool -> hT aliased into c1h ----
#pragma unroll
    for (int nt = 0; nt < 4; ++nt) {              // wave wv -> samples 2wv, 2wv+1; two q-halves
        const int s  = wv * 2 + (nt >> 1);
        const int qb = (nt & 1) * 16;
        const u16* bp = c1h + s * 1384 + (qb + lr) * 40 + lq * 8;
        bf16x8 bf0 = *(const bf16x8*)(bp);        // tap t=0
        bf16x8 bf1 = *(const bf16x8*)(bp + 40);   // t=1 (+1 row)
        bf16x8 bf2 = *(const bf16x8*)(bp + 80);   // t=2 (+2 rows)
        const int op = (qb + lr) >> 1;
#pragma unroll
        for (int mt = 0; mt < 4; ++mt) {          // interleaved epilogue: acc live = 4
            f32x4 acc = __builtin_amdgcn_mfma_f32_16x16x32_bf16(af[0][mt], bf0, bias2[mt], 0, 0, 0);
            acc = __builtin_amdgcn_mfma_f32_16x16x32_bf16(af[1][mt], bf1, acc, 0, 0, 0);
            acc = __builtin_amdgcn_mfma_f32_16x16x32_bf16(af[2][mt], bf2, acc, 0, 0, 0);
            float p0 = fmaxf(fmaxf(acc[0], __shfl_xor(acc[0], 1)), 0.f);
            float p1 = fmaxf(fmaxf(acc[1], __shfl_xor(acc[1], 1)), 0.f);
            float p2 = fmaxf(fmaxf(acc[2], __shfl_xor(acc[2], 1)), 0.f);
            float p3 = fmaxf(fmaxf(acc[3], __shfl_xor(acc[3], 1)), 0.f);
            if (!(lane & 1)) {
                *(uint2*)(c1h + s * 1384 + op * 72 + mt * 16 + lq * 4) =
                    make_uint2(cvt_pk_bf16(p0, p1), cvt_pk_bf16(p2, p3));
            }
        }
    }
    __syncthreads();   // barrier A: fc reads hT across all samples/waves

    // ---- fc via MFMA on 8 waves: g = wv&3 feature group, hf = wv>>2 kc-half.
    //      Fully unrolled, DUAL accumulator (2x8 chain instead of 16-deep). ----
    const int g  = wv & 3;
    const int hf = wv >> 2;
    const int n0 = g * 16;
    f32x4 accA = {0.f, 0.f, 0.f, 0.f};
    f32x4 accB = {0.f, 0.f, 0.f, 0.f};
    {
        const u16* ab0 = c1h + (size_t)lr * 1384 + lq * 8;
        const u16* bh0 = whi + (size_t)(n0 + lr) * 1024 + hf * 16 * 32 + lq * 8;
#pragma unroll
        for (int i = 0; i < 16; i += 2) {
            const int kcA = hf * 16 + i;
            const int kcB = kcA + 1;
            const int aoffA = (kcA >> 1) * 72 + (kcA & 1) * 32;
            const int aoffB = (kcB >> 1) * 72 + (kcB & 1) * 32;
            bf16x8 a0 = *(const bf16x8*)(ab0 + aoffA);
            bf16x8 a1 = *(const bf16x8*)(ab0 + aoffB);
            bf16x8 f0 = *(const bf16x8*)(bh0 + i * 32);
            bf16x8 f1 = *(const bf16x8*)(bh0 + (i + 1) * 32);
            accA = __builtin_amdgcn_mfma_f32_16x16x32_bf16(a0, f0, accA, 0, 0, 0);
            accB = __builtin_amdgcn_mfma_f32_16x16x32_bf16(a1, f1, accB, 0, 0, 0);
        }
    }
    const f32x4 acc0 = accA + accB;
    // ALL fc waves store partials: D row = lq*4+r = sample, col = lr -> feature n0+lr
    *(f32x4*)(&part2[hf * 1280 + (n0 + lr) * 20 + lq * 4]) = acc0;
    __syncthreads();   // barrier B (single): partials + tables visible to epilogue

    // ---- epilogue on WAVE 0 at full 64-lane utilization: s = lane>>2, L = lane&3.
    //      h = relu(p0 + p1 + fcb) fused inline from part2; cc=(c+L)&3 visit order
    //      staggers part2 banks by 20L -> conflict-free. ----
    if (wv == 0) {
        const int L = lane & 3;
        const int s = lane >> 2;

        float a0 = 0.f, a1 = 0.f, a2 = 0.f, a3 = 0.f;
#pragma unroll
        for (int i2 = 0; i2 < 4; ++i2) {
#pragma unroll
            for (int c = 0; c < 4; ++c) {
                int cc = (c + L) & 3;
                int ff = L * 16 + i2 * 4 + cc;
                float hx = fmaxf(part2[ff * 20 + s] + part2[1280 + ff * 20 + s] + fcbs[ff], 0.f);
                float4 pw = *(const float4*)&prews[ff * 4];
                a0 = fmaf(hx, pw.x, a0);
                a1 = fmaf(hx, pw.y, a1);
                a2 = fmaf(hx, pw.z, a2);
                a3 = fmaf(hx, pw.w, a3);
            }
        }
        // reduce across the 4 lanes of this sample (xor 1,2 stay within the lane quad)
        a0 += __shfl_xor(a0, 1); a0 += __shfl_xor(a0, 2);
        a1 += __shfl_xor(a1, 1); a1 += __shfl_xor(a1, 2);
        a2 += __shfl_xor(a2, 1); a2 += __shfl_xor(a2, 2);
        a3 += __shfl_xor(a3, 1); a3 += __shfl_xor(a3, 2);

        const float HP = 1.5707963267948966f;
        float qin[4] = { fast_tanh(a0 + preb[0]) * HP, fast_tanh(a1 + preb[1]) * HP,
                         fast_tanh(a2 + preb[2]) * HP, fast_tanh(a3 + preb[3]) * HP };

        float va[4], vb[4];
        const float RS = 0.70710678118654752f;
#pragma unroll
        for (int w = 0; w < 4; ++w) {
            float sw, cw;
            __sincosf(qin[w] * 0.5f, &sw, &cw);
            va[w] = (cw - sw) * RS;
            vb[w] = (sw + cw) * RS;
        }
        float sv[16];
#pragma unroll
        for (int jj = 0; jj < 16; ++jj) {
            float t = (jj & 8) ? vb[0] : va[0];
            t *= (jj & 4) ? vb[1] : va[1];
            t *= (jj & 2) ? vb[2] : va[2];
            t *= (jj & 1) ? vb[3] : va[3];
            sv[jj] = t;
        }
        float z0 = 0.f, z1 = 0.f, z2 = 0.f, z3 = 0.f;
#pragma unroll
        for (int rr = 0; rr < 4; ++rr) {
            const int r = L * 4 + rr;
            float m = 0.f;
#pragma unroll
            for (int jj = 0; jj < 16; ++jj) m = fmaf(Ms[r][jj], sv[jj], m);
            float p = m * m;
            z0 += (r & 8) ? -p : p;
            z1 += (r & 4) ? -p : p;
            z2 += (r & 2) ? -p : p;
            z3 += (r & 1) ? -p : p;
        }
        z0 += __shfl_xor(z0, 1); z0 += __shfl_xor(z0, 2);
        z1 += __shfl_xor(z1, 1); z1 += __shfl_xor(z1, 2);
        z2 += __shfl_xor(z2, 1); z2 += __shfl_xor(z2, 2);
        z3 += __shfl_xor(z3, 1); z3 += __shfl_xor(z3, 2);

        if (L == 0) {
            float t = postb[0] + z0 * postw[0] + z1 * postw[1] + z2 * postw[2] + z3 * postw[3];
            out[bs + s] = 1.f / (1.f + __expf(-t));
        }
    }
}

extern "C" void kernel_launch(void* const* d_in, const int* in_sizes, int n_in,
                              void* d_out, int out_size, void* d_ws, size_t ws_size,
                              hipStream_t stream) {
    const float* x     = (const float*)d_in[0];
    const float* w1    = (const float*)d_in[1];
    const float* b1    = (const float*)d_in[2];
    const float* w2    = (const float*)d_in[3];
    const float* b2    = (const float*)d_in[4];
    const float* fcw   = (const float*)d_in[5];
    const float* fcb   = (const float*)d_in[6];
    const float* prew  = (const float*)d_in[7];
    const float* preb  = (const float*)d_in[8];
    const float* qp    = (const float*)d_in[9];
    const float* postw = (const float*)d_in[10];
    const float* postb = (const float*)d_in[11];
    float* out = (float*)d_out;

    u16*   fwhi = (u16*)d_ws;                           // 64*1024 bf16 = 128 KiB
    float* Mg   = (float*)((char*)d_ws + 131072);       // 1 KiB
    u16*   w2b  = (u16*)((char*)d_ws + 132096);         // 12 KiB

    const int B = in_sizes[0] / 64;   // 32768

    prep_kernel<<<dim3(64), dim3(256), 0, stream>>>(fcw, w2, qp, fwhi, w2b, Mg);
    fused_kernel<<<dim3(B / 16), dim3(512), 0, stream>>>(x, w1, b1, w2b, b2,
                                                         fwhi, fcb, prew, preb,
                                                         postw, postb, Mg, out);
}